// Round 9
// baseline (4659.791 us; speedup 1.0000x reference)
//
#include <hip/hip_runtime.h>
#include <cstdint>
#include <cstddef>

#define B_ 512
#define T_ 2048
#define D_ 64
#define H_ 48
#define C_ 3
#define LCH 16           // chunk length
#define KCH 128          // chunks per batch
#define NC  65536        // total chains = B_*KCH

#define RECON_FLOATS ((size_t)B_ * T_ * D_)            // 67,108,864 floats (output 0)
#define LOGIT_FLOATS ((size_t)B_ * C_)                 // 1536 floats      (output 1)
#define Z_OFF        (RECON_FLOATS + LOGIT_FLOATS)     // z region         (output 2)
// scratch regions stashed inside the recon region (dec overwrites them LAST):
#define UT_OFF   ((size_t)0)                           // uT[s][c][48]: 50,331,648 floats
#define S0_OFF   ((size_t)50331648)                    // S0[c][48]   :  3,145,728
#define MIN_OFF  ((size_t)53477376)                    // M_in[c][48] :  3,145,728
#define ZP_OFF   ((size_t)56623104)                    // zsum_part[c][48]
#define A16_OFF  ((size_t)59768832)                    // A^16: 2304 floats (ends 59,771,136 < 67M)

// ---------------- encoder GEMM: uT[s][c][i] = x row . Wenc^T + (benc+bmem) ----------------
__global__ __launch_bounds__(128) void k_enc(
    const float* __restrict__ x, const float* __restrict__ Wenc,
    const float* __restrict__ benc, const float* __restrict__ bmem,
    float* __restrict__ out)
{
    __shared__ float sx[128][68];
    __shared__ float sw[48][68];
    __shared__ float sbe[48];

    const int tid = threadIdx.x;

    {
        const float4* wf4 = reinterpret_cast<const float4*>(Wenc);
        #pragma unroll
        for (int m = 0; m < 6; ++m) {
            const int idx = tid + 128 * m;
            const int c = idx >> 4, d4 = idx & 15;
            *reinterpret_cast<float4*>(&sw[c][d4 * 4]) = wf4[idx];
        }
    }
    if (tid < 48) sbe[tid] = benc[tid] + bmem[tid];

    {
        const float4* xf4 = reinterpret_cast<const float4*>(x) + (size_t)blockIdx.x * 2048;
        #pragma unroll
        for (int m = 0; m < 16; ++m) {
            const int idx = tid + 128 * m;
            const int row = idx >> 4, d4 = idx & 15;
            *reinterpret_cast<float4*>(&sx[row][d4 * 4]) = xf4[idx];
        }
    }
    __syncthreads();

    const int lane = tid & 63;
    const int wv   = tid >> 6;
    const int rg   = lane >> 2;
    const int cg   = lane & 3;
    const int rowb = wv * 64 + rg;
    const int colb = cg * 12;

    float acc[4][12];
    {
        float bia[12];
        #pragma unroll
        for (int m = 0; m < 3; ++m)
            *reinterpret_cast<float4*>(&bia[4 * m]) = *reinterpret_cast<const float4*>(&sbe[colb + 4 * m]);
        #pragma unroll
        for (int k = 0; k < 4; ++k)
            #pragma unroll
            for (int i = 0; i < 12; ++i) acc[k][i] = bia[i];
    }

    #pragma unroll 2
    for (int d4 = 0; d4 < 16; ++d4) {
        float4 xf[4];
        #pragma unroll
        for (int k = 0; k < 4; ++k)
            xf[k] = *reinterpret_cast<const float4*>(&sx[rowb + 16 * k][d4 * 4]);
        #pragma unroll
        for (int i = 0; i < 12; ++i) {
            const float4 wvv = *reinterpret_cast<const float4*>(&sw[colb + i][d4 * 4]);
            #pragma unroll
            for (int k = 0; k < 4; ++k)
                acc[k][i] = fmaf(xf[k].x, wvv.x, fmaf(xf[k].y, wvv.y,
                             fmaf(xf[k].z, wvv.z, fmaf(xf[k].w, wvv.w, acc[k][i]))));
        }
    }

    #pragma unroll
    for (int k = 0; k < 4; ++k) {
        const int rr = blockIdx.x * 128 + rowb + 16 * k;   // global row (b,t)
        const int bb = rr >> 11;
        const int tt = rr & 2047;
        const int ss = tt & 15;
        const int kk = tt >> 4;
        float* dst = out + ((size_t)ss * NC + ((size_t)bb << 7) + kk) * 48 + colb;
        #pragma unroll
        for (int m = 0; m < 3; ++m)
            *reinterpret_cast<float4*>(dst + 4 * m) =
                make_float4(acc[k][4 * m], acc[k][4 * m + 1], acc[k][4 * m + 2], acc[k][4 * m + 3]);
    }
}

// ---------------- A^16 via 4 squarings (one small block) ----------------
__global__ __launch_bounds__(576) void k_powA(
    const float* __restrict__ Wmem, float* __restrict__ out)
{
    __shared__ float a0[48 * 49];
    __shared__ float a1[48 * 49];
    const int tid = threadIdx.x;

    for (int idx = tid; idx < 2304; idx += 576) {
        const int i = idx / 48, j = idx - i * 48;
        a0[i * 49 + j] = 0.1f * Wmem[idx] + (i == j ? 0.9f : 0.0f);
    }
    __syncthreads();

    float* src = a0;
    float* dst = a1;
    #pragma unroll 1
    for (int it = 0; it < 4; ++it) {
        float v[4];
        #pragma unroll
        for (int q = 0; q < 4; ++q) {
            const int o = tid + 576 * q;
            const int i = o / 48, j = o - i * 48;
            float acc = 0.f;
            #pragma unroll
            for (int k = 0; k < 48; ++k)
                acc = fmaf(src[i * 49 + k], src[k * 49 + j], acc);
            v[q] = acc;
        }
        #pragma unroll
        for (int q = 0; q < 4; ++q) {
            const int o = tid + 576 * q;
            const int i = o / 48, j = o - i * 48;
            dst[i * 49 + j] = v[q];
        }
        __syncthreads();
        float* t = src; src = dst; dst = t;
    }
    for (int idx = tid; idx < 2304; idx += 576) {
        const int i = idx / 48, j = idx - i * 48;
        out[A16_OFF + idx] = src[i * 49 + j];
    }
}

// mn += A*mo, A^T staged in LDS col-major (sAT[j*48+i] = A[i][j]); uniform broadcasts
__device__ __forceinline__ void amv(const float* __restrict__ sAT,
                                    const float (&mo)[48], float (&mn)[48])
{
    #pragma unroll
    for (int j = 0; j < 48; ++j) {
        const float mj = mo[j];
        #pragma unroll
        for (int i4 = 0; i4 < 12; ++i4) {
            const float4 a = *reinterpret_cast<const float4*>(sAT + j * 48 + i4 * 4);
            mn[i4 * 4 + 0] = fmaf(a.x, mj, mn[i4 * 4 + 0]);
            mn[i4 * 4 + 1] = fmaf(a.y, mj, mn[i4 * 4 + 1]);
            mn[i4 * 4 + 2] = fmaf(a.z, mj, mn[i4 * 4 + 2]);
            mn[i4 * 4 + 3] = fmaf(a.w, mj, mn[i4 * 4 + 3]);
        }
    }
}

// ---------------- phase 1: zero-init chunk-end states; chain-per-lane ----------------
__global__ __launch_bounds__(256) void k_p1(
    const float* __restrict__ Wmem, float* __restrict__ out)
{
    __shared__ float sAT[48 * 48];
    const int tid = threadIdx.x;
    for (int idx = tid; idx < 2304; idx += 256) {
        const int i = idx / 48, j = idx - i * 48;
        sAT[j * 48 + i] = 0.1f * Wmem[idx] + (i == j ? 0.9f : 0.0f);
    }
    __syncthreads();

    const size_t c = (size_t)blockIdx.x * 256 + tid;
    const float* ub = out + c * 48;            // uT[0][c][*]; step stride NC*48

    float mo[48];
    #pragma unroll
    for (int i = 0; i < 48; ++i) mo[i] = 0.f;

    float ubuf[48];
    #pragma unroll
    for (int q = 0; q < 12; ++q)
        *reinterpret_cast<float4*>(&ubuf[4 * q]) = *reinterpret_cast<const float4*>(ub + 4 * q);

    #pragma unroll 1
    for (int s = 0; s < LCH; ++s) {
        float mn[48];
        #pragma unroll
        for (int i = 0; i < 48; ++i) mn[i] = ubuf[i];
        // prefetch next step's u (clamped redundant read at s=15; hidden under matvec)
        const float* un = ub + (size_t)(s + 1 < LCH ? s + 1 : LCH - 1) * ((size_t)NC * 48);
        #pragma unroll
        for (int q = 0; q < 12; ++q)
            *reinterpret_cast<float4*>(&ubuf[4 * q]) = *reinterpret_cast<const float4*>(un + 4 * q);
        amv(sAT, mo, mn);
        #pragma unroll
        for (int i = 0; i < 48; ++i) mo[i] = mn[i];
    }

    float4* dst = reinterpret_cast<float4*>(out + S0_OFF + c * 48);
    #pragma unroll
    for (int q = 0; q < 12; ++q)
        dst[q] = make_float4(mo[4 * q], mo[4 * q + 1], mo[4 * q + 2], mo[4 * q + 3]);
}

// ---------------- phase 2: sequential boundary combine per batch (readlane) ----------------
__global__ __launch_bounds__(64) void k_p2(float* __restrict__ out)
{
    const int lane = threadIdx.x;
    const int b    = blockIdx.x;
    const int h    = lane < H_ ? lane : 0;

    const float* A16 = out + A16_OFF;
    float w16[48];
    #pragma unroll
    for (int j = 0; j < 48; ++j) w16[j] = A16[h * 48 + j];

    float E = 0.f;
    #pragma unroll 1
    for (int k = 0; k < KCH; ++k) {
        const size_t c = ((size_t)b << 7) | k;
        if (lane < H_) out[MIN_OFF + c * 48 + h] = E;   // state entering chunk k
        const float s0 = out[S0_OFF + c * 48 + h];
        float a0 = s0, a1 = 0.f, a2 = 0.f, a3 = 0.f, a4 = 0.f, a5 = 0.f, a6 = 0.f, a7 = 0.f;
        #pragma unroll
        for (int g = 0; g < 6; ++g) {
            const int j = 8 * g;
            const float m0 = __int_as_float(__builtin_amdgcn_readlane(__float_as_int(E), j + 0));
            const float m1 = __int_as_float(__builtin_amdgcn_readlane(__float_as_int(E), j + 1));
            const float m2 = __int_as_float(__builtin_amdgcn_readlane(__float_as_int(E), j + 2));
            const float m3 = __int_as_float(__builtin_amdgcn_readlane(__float_as_int(E), j + 3));
            const float m4 = __int_as_float(__builtin_amdgcn_readlane(__float_as_int(E), j + 4));
            const float m5 = __int_as_float(__builtin_amdgcn_readlane(__float_as_int(E), j + 5));
            const float m6 = __int_as_float(__builtin_amdgcn_readlane(__float_as_int(E), j + 6));
            const float m7 = __int_as_float(__builtin_amdgcn_readlane(__float_as_int(E), j + 7));
            a0 = fmaf(m0, w16[j + 0], a0);
            a1 = fmaf(m1, w16[j + 1], a1);
            a2 = fmaf(m2, w16[j + 2], a2);
            a3 = fmaf(m3, w16[j + 3], a3);
            a4 = fmaf(m4, w16[j + 4], a4);
            a5 = fmaf(m5, w16[j + 5], a5);
            a6 = fmaf(m6, w16[j + 6], a6);
            a7 = fmaf(m7, w16[j + 7], a7);
        }
        E = ((a0 + a1) + (a2 + a3)) + ((a4 + a5) + (a6 + a7));
    }
}

// ---------------- phase 3: re-run chunks from corrected starts; emit z + zsum partials ----------------
__global__ __launch_bounds__(256) void k_p3(
    const float* __restrict__ Wmem, float* __restrict__ out)
{
    __shared__ float sAT[48 * 48];
    const int tid = threadIdx.x;
    for (int idx = tid; idx < 2304; idx += 256) {
        const int i = idx / 48, j = idx - i * 48;
        sAT[j * 48 + i] = 0.1f * Wmem[idx] + (i == j ? 0.9f : 0.0f);
    }
    __syncthreads();

    const size_t c = (size_t)blockIdx.x * 256 + tid;
    const float* ub = out + c * 48;
    const int bb = (int)(c >> 7), kk = (int)(c & 127);
    float* zb = out + Z_OFF + ((size_t)bb * T_ + (size_t)kk * LCH) * 48;

    float mo[48];
    {
        const float4* m4 = reinterpret_cast<const float4*>(out + MIN_OFF + c * 48);
        #pragma unroll
        for (int q = 0; q < 12; ++q)
            *reinterpret_cast<float4*>(&mo[4 * q]) = m4[q];
    }
    float zsum[48];
    #pragma unroll
    for (int i = 0; i < 48; ++i) zsum[i] = 0.f;

    float ubuf[48];
    #pragma unroll
    for (int q = 0; q < 12; ++q)
        *reinterpret_cast<float4*>(&ubuf[4 * q]) = *reinterpret_cast<const float4*>(ub + 4 * q);

    const float kExp = -0.14426950408889634f;  // -0.1*log2(e): z = sigmoid(ms/10)

    #pragma unroll 1
    for (int s = 0; s < LCH; ++s) {
        float mn[48];
        #pragma unroll
        for (int i = 0; i < 48; ++i) mn[i] = ubuf[i];
        const float* un = ub + (size_t)(s + 1 < LCH ? s + 1 : LCH - 1) * ((size_t)NC * 48);
        #pragma unroll
        for (int q = 0; q < 12; ++q)
            *reinterpret_cast<float4*>(&ubuf[4 * q]) = *reinterpret_cast<const float4*>(un + 4 * q);
        amv(sAT, mo, mn);
        // z = sigmoid(mn/10), accumulate zsum, store
        float* zd = zb + (size_t)s * 48;
        #pragma unroll
        for (int q = 0; q < 12; ++q) {
            float zq[4];
            #pragma unroll
            for (int e = 0; e < 4; ++e) {
                const float ex = __builtin_amdgcn_exp2f(mn[4 * q + e] * kExp);
                zq[e] = __builtin_amdgcn_rcpf(1.0f + ex);
                zsum[4 * q + e] += zq[e];
            }
            *reinterpret_cast<float4*>(zd + 4 * q) = make_float4(zq[0], zq[1], zq[2], zq[3]);
        }
        #pragma unroll
        for (int i = 0; i < 48; ++i) mo[i] = mn[i];
    }

    float4* zp = reinterpret_cast<float4*>(out + ZP_OFF + c * 48);
    #pragma unroll
    for (int q = 0; q < 12; ++q)
        zp[q] = make_float4(zsum[4 * q], zsum[4 * q + 1], zsum[4 * q + 2], zsum[4 * q + 3]);
}

// ---------------- classifier: reduce zsum partials, logits (before dec overwrites) ----------------
__global__ __launch_bounds__(64) void k_cls(
    const float* __restrict__ Wcls, const float* __restrict__ bcls,
    float* __restrict__ out)
{
    __shared__ float sz[48];
    const int lane = threadIdx.x;
    const int b    = blockIdx.x;
    if (lane < 48) {
        float acc = 0.f;
        #pragma unroll 4
        for (int k = 0; k < KCH; ++k)
            acc += out[ZP_OFF + (((size_t)b << 7) | k) * 48 + lane];
        sz[lane] = acc;
    }
    __syncthreads();
    if (lane < C_) {
        float acc = 0.f;
        #pragma unroll
        for (int h = 0; h < 48; ++h) acc = fmaf(sz[h], Wcls[lane * 48 + h], acc);
        out[RECON_FLOATS + (size_t)b * C_ + lane] = acc * (1.0f / (float)T_) + bcls[lane];
    }
}

// ---------------- decoder GEMM: recon = z . Wdec^T + bdec (round-8 verbatim) ----------------
__global__ __launch_bounds__(256) void k_dec(
    const float* __restrict__ Wdec, const float* __restrict__ bdec,
    float* __restrict__ out)
{
    __shared__ float sz[256][52];
    __shared__ float swT[48][68];
    __shared__ float sbd[64];

    const int tid = threadIdx.x;

    #pragma unroll
    for (int m = 0; m < 12; ++m) {
        const int idx = tid + 256 * m;
        const int d = idx / 48, hh = idx - d * 48;
        swT[hh][d] = Wdec[idx];
    }
    if (tid < 64) sbd[tid] = bdec[tid];

    {
        const float4* zf4 = reinterpret_cast<const float4*>(out + Z_OFF) + (size_t)blockIdx.x * 3072;
        #pragma unroll
        for (int m = 0; m < 12; ++m) {
            const int idx = tid + 256 * m;
            const int row = idx / 12, c4 = idx - row * 12;
            *reinterpret_cast<float4*>(&sz[row][c4 * 4]) = zf4[idx];
        }
    }
    __syncthreads();

    const int lane = tid & 63;
    const int wv   = tid >> 6;
    const int rg   = lane >> 3;
    const int cg   = lane & 7;
    const int rowb = wv * 64 + rg;
    const int colb = cg * 8;

    float acc[8][8];
    {
        float bd[8];
        *reinterpret_cast<float4*>(&bd[0]) = *reinterpret_cast<const float4*>(&sbd[colb]);
        *reinterpret_cast<float4*>(&bd[4]) = *reinterpret_cast<const float4*>(&sbd[colb + 4]);
        #pragma unroll
        for (int k = 0; k < 8; ++k)
            #pragma unroll
            for (int c = 0; c < 8; ++c) acc[k][c] = bd[c];
    }

    #pragma unroll 2
    for (int h4 = 0; h4 < 12; ++h4) {
        float4 zf[8];
        #pragma unroll
        for (int k = 0; k < 8; ++k)
            zf[k] = *reinterpret_cast<const float4*>(&sz[rowb + 8 * k][h4 * 4]);
        #pragma unroll
        for (int j = 0; j < 4; ++j) {
            const float4 w0 = *reinterpret_cast<const float4*>(&swT[h4 * 4 + j][colb]);
            const float4 w1 = *reinterpret_cast<const float4*>(&swT[h4 * 4 + j][colb + 4]);
            #pragma unroll
            for (int k = 0; k < 8; ++k) {
                const float zv = j == 0 ? zf[k].x : (j == 1 ? zf[k].y : (j == 2 ? zf[k].z : zf[k].w));
                acc[k][0] = fmaf(zv, w0.x, acc[k][0]);
                acc[k][1] = fmaf(zv, w0.y, acc[k][1]);
                acc[k][2] = fmaf(zv, w0.z, acc[k][2]);
                acc[k][3] = fmaf(zv, w0.w, acc[k][3]);
                acc[k][4] = fmaf(zv, w1.x, acc[k][4]);
                acc[k][5] = fmaf(zv, w1.y, acc[k][5]);
                acc[k][6] = fmaf(zv, w1.z, acc[k][6]);
                acc[k][7] = fmaf(zv, w1.w, acc[k][7]);
            }
        }
    }

    const size_t row0 = (size_t)blockIdx.x * 256 + rowb;
    #pragma unroll
    for (int k = 0; k < 8; ++k) {
        float* dst = out + (row0 + 8 * k) * 64 + colb;
        *reinterpret_cast<float4*>(dst)     = make_float4(acc[k][0], acc[k][1], acc[k][2], acc[k][3]);
        *reinterpret_cast<float4*>(dst + 4) = make_float4(acc[k][4], acc[k][5], acc[k][6], acc[k][7]);
    }
}

extern "C" void kernel_launch(void* const* d_in, const int* in_sizes, int n_in,
                              void* d_out, int out_size, void* d_ws, size_t ws_size,
                              hipStream_t stream) {
    const float* x    = (const float*)d_in[0];
    const float* Wenc = (const float*)d_in[1];
    const float* benc = (const float*)d_in[2];
    const float* Wmem = (const float*)d_in[3];
    const float* bmem = (const float*)d_in[4];
    const float* Wdec = (const float*)d_in[5];
    const float* bdec = (const float*)d_in[6];
    const float* Wcls = (const float*)d_in[7];
    const float* bcls = (const float*)d_in[8];
    float* out = (float*)d_out;

    k_powA<<<dim3(1), dim3(576), 0, stream>>>(Wmem, out);
    k_enc<<<dim3((B_ * T_) / 128), dim3(128), 0, stream>>>(x, Wenc, benc, bmem, out);
    k_p1<<<dim3(NC / 256), dim3(256), 0, stream>>>(Wmem, out);
    k_p2<<<dim3(B_), dim3(64), 0, stream>>>(out);
    k_p3<<<dim3(NC / 256), dim3(256), 0, stream>>>(Wmem, out);
    k_cls<<<dim3(B_), dim3(64), 0, stream>>>(Wcls, bcls, out);
    k_dec<<<dim3((B_ * T_) / 256), dim3(256), 0, stream>>>(Wdec, bdec, out);
}